// Round 1
// baseline (1221.109 us; speedup 1.0000x reference)
//
#include <hip/hip_runtime.h>

#define N_NODES 50000
#define N_EDGES 600000
#define F_NODE 128
#define F_EDGE 32
#define MSG 32
#define EDGE_IN 288   // 2*F_NODE + F_EDGE
#define NODE_IN 160   // F_NODE + MSG

// ---------------------------------------------------------------------------
// Edge kernel: messages = relu([nf[n0]|nf[n1]|ef] @ We + be); atomicAdd into
// msg_sums[n0]. 256 edges/block, 256 threads.
// LDS: We full (36 KB) + msg_in transposed K-chunk [32][256] (32 KB) + indices.
// Thread tile: 4 edges x 8 outputs (acc[4][8]).
// ---------------------------------------------------------------------------
__global__ __launch_bounds__(256, 2)
void edge_msg_kernel(const float* __restrict__ nf,
                     const int* __restrict__ idx,     // [2][E]
                     const float* __restrict__ ef,    // [E][32]
                     const float* __restrict__ We,    // [288][32]
                     const float* __restrict__ be,    // [32]
                     float* __restrict__ msg_sums)    // [N][32]
{
    __shared__ float sWe[EDGE_IN * MSG];   // 36 KB
    __shared__ float sMsgT[32 * 256];      // 32 KB, [k][edge] layout
    __shared__ int sN0[256];
    __shared__ int sN1[256];

    const int tid = threadIdx.x;
    const int e0 = blockIdx.x * 256;

    // Stage full We (2304 float4, 9 per thread, coalesced)
    {
        const float4* We4 = (const float4*)We;
        float4* sWe4 = (float4*)sWe;
        for (int i = tid; i < EDGE_IN * MSG / 4; i += 256) sWe4[i] = We4[i];
    }
    // Stage this block's edge indices
    {
        int e = e0 + tid;
        int v0 = 0, v1 = 0;
        if (e < N_EDGES) { v0 = idx[e]; v1 = idx[N_EDGES + e]; }
        sN0[tid] = v0; sN1[tid] = v1;
    }

    const int eg = tid & 63;   // edge group: edges 4*eg .. 4*eg+3
    const int og = tid >> 6;   // output group: cols og*8 .. og*8+7 (wave-uniform)

    float acc[4][8];
#pragma unroll
    for (int i = 0; i < 4; ++i)
#pragma unroll
        for (int j = 0; j < 8; ++j) acc[i][j] = 0.f;

    // 9 K-chunks of 32: [0,128)=nf[n0], [128,256)=nf[n1], [256,288)=ef
    for (int kc = 0; kc < 9; ++kc) {
        __syncthreads();   // also covers the initial We/idx staging at kc=0
        {
            const float* src;
            if (kc < 4)      src = nf + (size_t)sN0[tid] * F_NODE + kc * 32;
            else if (kc < 8) src = nf + (size_t)sN1[tid] * F_NODE + (kc - 4) * 32;
            else {
                int e = e0 + tid; if (e >= N_EDGES) e = N_EDGES - 1;
                src = ef + (size_t)e * F_EDGE;
            }
            const float4* src4 = (const float4*)src;
#pragma unroll
            for (int q = 0; q < 8; ++q) {
                float4 v = src4[q];
                // transposed store: stride 256 floats between k rows;
                // per-instruction lanes write consecutive e -> 2-way (free)
                sMsgT[(q * 4 + 0) * 256 + tid] = v.x;
                sMsgT[(q * 4 + 1) * 256 + tid] = v.y;
                sMsgT[(q * 4 + 2) * 256 + tid] = v.z;
                sMsgT[(q * 4 + 3) * 256 + tid] = v.w;
            }
        }
        __syncthreads();

        const float* weB = sWe + kc * 32 * MSG + og * 8;
#pragma unroll
        for (int k = 0; k < 32; ++k) {
            // contiguous wave-wide b128: conflict-free
            float4 m = *(const float4*)&sMsgT[k * 256 + 4 * eg];
            // wave-uniform address: LDS broadcast
            float4 w0 = *(const float4*)&weB[k * MSG];
            float4 w1 = *(const float4*)&weB[k * MSG + 4];
            float ma[4] = { m.x, m.y, m.z, m.w };
            float wv[8] = { w0.x, w0.y, w0.z, w0.w, w1.x, w1.y, w1.z, w1.w };
#pragma unroll
            for (int i = 0; i < 4; ++i)
#pragma unroll
                for (int j = 0; j < 8; ++j) acc[i][j] += ma[i] * wv[j];
        }
    }

    float bias[8];
#pragma unroll
    for (int j = 0; j < 8; ++j) bias[j] = be[og * 8 + j];

#pragma unroll
    for (int i = 0; i < 4; ++i) {
        int el = 4 * eg + i;
        int e = e0 + el;
        if (e < N_EDGES) {
            float* dst = msg_sums + (size_t)sN0[el] * MSG + og * 8;
#pragma unroll
            for (int j = 0; j < 8; ++j) {
                float v = acc[i][j] + bias[j];
                v = v > 0.f ? v : 0.f;
                atomicAdd(dst + j, v);
            }
        }
    }
}

// ---------------------------------------------------------------------------
// Node kernel: out = relu([nf | msg_sums] @ Wn + bn). 64 nodes/block,
// 256 threads. Wn staged per-K-chunk (16 KB), node_in transposed chunk (8 KB).
// Thread tile: 2 nodes x 16 outputs.
// ---------------------------------------------------------------------------
__global__ __launch_bounds__(256, 4)
void node_kernel(const float* __restrict__ nf,
                 const float* __restrict__ msg_sums,
                 const float* __restrict__ Wn,      // [160][128]
                 const float* __restrict__ bn,      // [128]
                 float* __restrict__ out)           // [N][128]
{
    __shared__ float sInT[32 * 64];    // 8 KB, [k][node]
    __shared__ float sWn[32 * 128];    // 16 KB

    const int tid = threadIdx.x;
    const int n0b = blockIdx.x * 64;

    const int ng = tid & 31;   // nodes 2*ng, 2*ng+1
    const int og = tid >> 5;   // outs og*16 .. +15 (uniform per half-wave)

    float acc[2][16];
#pragma unroll
    for (int i = 0; i < 2; ++i)
#pragma unroll
        for (int j = 0; j < 16; ++j) acc[i][j] = 0.f;

    // 5 K-chunks of 32: [0,128)=nf, [128,160)=msg_sums
    for (int kc = 0; kc < 5; ++kc) {
        __syncthreads();
        // stage Wn chunk [32][128] (direct copy, coalesced)
        {
            const float4* w4 = (const float4*)(Wn + (size_t)kc * 32 * 128);
            float4* s4 = (float4*)sWn;
#pragma unroll
            for (int i = 0; i < 4; ++i) s4[tid + 256 * i] = w4[tid + 256 * i];
        }
        // stage node_in transposed chunk [32][64]
        {
            int nl = tid >> 2;          // 0..63
            int q  = tid & 3;
            int n = n0b + nl; if (n >= N_NODES) n = N_NODES - 1;
            const float* src = (kc < 4) ? (nf + (size_t)n * F_NODE + kc * 32)
                                        : (msg_sums + (size_t)n * MSG);
            const float4* src4 = (const float4*)src;
#pragma unroll
            for (int h = 0; h < 2; ++h) {
                float4 v = src4[q * 2 + h];
                int kl = q * 8 + h * 4;
                sInT[(kl + 0) * 64 + nl] = v.x;
                sInT[(kl + 1) * 64 + nl] = v.y;
                sInT[(kl + 2) * 64 + nl] = v.z;
                sInT[(kl + 3) * 64 + nl] = v.w;
            }
        }
        __syncthreads();

#pragma unroll
        for (int k = 0; k < 32; ++k) {
            float2 m = *(const float2*)&sInT[k * 64 + 2 * ng];
            const float* wr = &sWn[k * 128 + og * 16];
            float4 w0 = *(const float4*)&wr[0];
            float4 w1 = *(const float4*)&wr[4];
            float4 w2 = *(const float4*)&wr[8];
            float4 w3 = *(const float4*)&wr[12];
            float ma[2] = { m.x, m.y };
            float wv[16] = { w0.x,w0.y,w0.z,w0.w, w1.x,w1.y,w1.z,w1.w,
                             w2.x,w2.y,w2.z,w2.w, w3.x,w3.y,w3.z,w3.w };
#pragma unroll
            for (int i = 0; i < 2; ++i)
#pragma unroll
                for (int j = 0; j < 16; ++j) acc[i][j] += ma[i] * wv[j];
        }
    }

    float bias[16];
#pragma unroll
    for (int j = 0; j < 16; ++j) bias[j] = bn[og * 16 + j];

#pragma unroll
    for (int i = 0; i < 2; ++i) {
        int n = n0b + 2 * ng + i;
        if (n < N_NODES) {
            float* dst = out + (size_t)n * F_NODE + og * 16;
#pragma unroll
            for (int j = 0; j < 16; j += 4) {
                float4 v;
                v.x = fmaxf(acc[i][j + 0] + bias[j + 0], 0.f);
                v.y = fmaxf(acc[i][j + 1] + bias[j + 1], 0.f);
                v.z = fmaxf(acc[i][j + 2] + bias[j + 2], 0.f);
                v.w = fmaxf(acc[i][j + 3] + bias[j + 3], 0.f);
                *(float4*)(dst + j) = v;
            }
        }
    }
}

extern "C" void kernel_launch(void* const* d_in, const int* in_sizes, int n_in,
                              void* d_out, int out_size, void* d_ws, size_t ws_size,
                              hipStream_t stream) {
    const float* nf  = (const float*)d_in[0];
    const int*   idx = (const int*)d_in[1];
    const float* ef  = (const float*)d_in[2];
    const float* We  = (const float*)d_in[3];
    const float* be  = (const float*)d_in[4];
    const float* Wn  = (const float*)d_in[5];
    const float* bn  = (const float*)d_in[6];
    float* out = (float*)d_out;
    float* msg_sums = (float*)d_ws;   // [N_NODES][MSG] fp32, 6.4 MB

    hipMemsetAsync(msg_sums, 0, (size_t)N_NODES * MSG * sizeof(float), stream);

    edge_msg_kernel<<<(N_EDGES + 255) / 256, 256, 0, stream>>>(
        nf, idx, ef, We, be, msg_sums);

    node_kernel<<<(N_NODES + 63) / 64, 256, 0, stream>>>(
        nf, msg_sums, Wn, bn, out);
}

// Round 4
// 688.272 us; speedup vs baseline: 1.7742x; 1.7742x over previous
//
#include <hip/hip_runtime.h>

#define N_NODES 50000
#define N_EDGES 600000
#define F_NODE 128
#define F_EDGE 32
#define MSG 32
#define NPB 64          // nodes per fused block

// ---------------------------------------------------------------------------
// CSR pass 1: degree histogram (600K int atomics over 50K bins)
// ---------------------------------------------------------------------------
__global__ void count_kernel(const int* __restrict__ idx, int* __restrict__ deg) {
    int e = blockIdx.x * 256 + threadIdx.x;
    if (e < N_EDGES) atomicAdd(&deg[idx[e]], 1);
}

// ---------------------------------------------------------------------------
// CSR pass 2: in-place exclusive scan (deg -> start offsets), 1 block x 1024.
// Each element read-then-overwritten by the same thread -> in-place safe.
// ---------------------------------------------------------------------------
__global__ __launch_bounds__(1024)
void scan_kernel(int* __restrict__ deg_cursor) {
    __shared__ int part[1024];
    const int t = threadIdx.x;
    const int CH = (N_NODES + 1023) / 1024;   // 49
    int lo = t * CH;
    int hi = lo + CH; if (hi > N_NODES) hi = N_NODES;
    if (lo > N_NODES) lo = N_NODES;
    int s = 0;
    for (int i = lo; i < hi; ++i) s += deg_cursor[i];
    part[t] = s;
    __syncthreads();
    for (int d = 1; d < 1024; d <<= 1) {
        int v = (t >= d) ? part[t - d] : 0;
        __syncthreads();
        part[t] += v;
        __syncthreads();
    }
    int run = (t > 0) ? part[t - 1] : 0;   // exclusive prefix of my chunk
    for (int i = lo; i < hi; ++i) {
        int d = deg_cursor[i];
        deg_cursor[i] = run;               // start offset (becomes cursor)
        run += d;
    }
}

// ---------------------------------------------------------------------------
// CSR pass 3: scatter edge ids into destination-sorted order.
// Afterwards cursor[n] == end offset of node n (== offsets[n+1]).
// ---------------------------------------------------------------------------
__global__ void scatter_kernel(const int* __restrict__ idx, int* __restrict__ cursor,
                               int* __restrict__ perm) {
    int e = blockIdx.x * 256 + threadIdx.x;
    if (e < N_EDGES) {
        int p = atomicAdd(&cursor[idx[e]], 1);
        perm[p] = e;
    }
}

// ---------------------------------------------------------------------------
// Fused kernel: one block owns 64 nodes and ALL their incoming edges
// (contiguous in sorted order). Phase 1: 256-edge chunks through the proven
// edge-GEMM inner loop; relu'd messages accumulate into LDS sMsgAcc[64][33]
// via LDS atomics (local node id = n0 - n0b). Phase 2: proven node GEMM,
// msg chunk read from LDS. No global msg_sums, no global float atomics.
// LDS: 32KB sBuf (edge msg^T, reused as sInT+sWn) + 4KB sWeC + 8.25KB
// sMsgAcc + 3KB indices = ~47.5KB -> 3 blocks/CU.
// ---------------------------------------------------------------------------
__global__ __launch_bounds__(256, 3)
void fused_kernel(const float* __restrict__ nf,
                  const int* __restrict__ idx,      // [2][E]
                  const float* __restrict__ ef,     // [E][32]
                  const float* __restrict__ We,     // [288][32]
                  const float* __restrict__ be,     // [32]
                  const float* __restrict__ Wn,     // [160][128]
                  const float* __restrict__ bn,     // [128]
                  const int* __restrict__ perm,     // [E] sorted edge ids
                  const int* __restrict__ cursor,   // [N] end offsets
                  float* __restrict__ out)          // [N][128]
{
    __shared__ float sBuf[32 * 256];    // edge msg^T [32][256]; ph2: sInT+sWn
    __shared__ float sWeC[32 * 32];     // We K-chunk
    __shared__ float sMsgAcc[NPB * 33]; // per-node msg accumulator (padded)
    __shared__ int sEid[256];
    __shared__ int sLn[256];            // local node id per staged edge, -1 pad
    __shared__ int sN1[256];

    const int tid = threadIdx.x;
    const int n0b = blockIdx.x * NPB;
    const int nEnd = (n0b + NPB < N_NODES) ? (n0b + NPB) : N_NODES;

    for (int i = tid; i < NPB * 33; i += 256) sMsgAcc[i] = 0.f;

    const int rs = (n0b == 0) ? 0 : cursor[n0b - 1];
    const int re = cursor[nEnd - 1];

    const int eg = tid & 63;   // edges 4*eg .. 4*eg+3
    const int og = tid >> 6;   // cols og*8 .. +7 (wave-uniform)

    float ebias[8];
#pragma unroll
    for (int j = 0; j < 8; ++j) ebias[j] = be[og * 8 + j];

    // ================= Phase 1: edge chunks =================
    for (int cs = rs; cs < re; cs += 256) {
        __syncthreads();   // prior chunk's sBuf/sLn reads complete
        {
            int e = cs + tid;
            bool valid = e < re;
            int pe = valid ? perm[e] : 0;
            int ln = -1, v1 = 0;
            if (valid) { ln = idx[pe] - n0b; v1 = idx[N_EDGES + pe]; }
            sEid[tid] = pe;
            sLn[tid] = ln;
            sN1[tid] = v1;
        }

        float acc[4][8];
#pragma unroll
        for (int i = 0; i < 4; ++i)
#pragma unroll
            for (int j = 0; j < 8; ++j) acc[i][j] = 0.f;

        // 9 K-chunks of 32: [0,128)=nf[n0], [128,256)=nf[n1], [256,288)=ef
        for (int kc = 0; kc < 9; ++kc) {
            __syncthreads();
            ((float4*)sWeC)[tid] = ((const float4*)(We + kc * 32 * MSG))[tid];
            {
                const float* src;
                if (kc < 4) {
                    int ln = sLn[tid]; if (ln < 0) ln = 0;           // own lane
                    src = nf + (size_t)(n0b + ln) * F_NODE + kc * 32;
                } else if (kc < 8) {
                    src = nf + (size_t)sN1[tid] * F_NODE + (kc - 4) * 32;
                } else {
                    src = ef + (size_t)sEid[tid] * F_EDGE;
                }
                const float4* src4 = (const float4*)src;
#pragma unroll
                for (int q = 0; q < 8; ++q) {
                    float4 v = src4[q];
                    sBuf[(q * 4 + 0) * 256 + tid] = v.x;
                    sBuf[(q * 4 + 1) * 256 + tid] = v.y;
                    sBuf[(q * 4 + 2) * 256 + tid] = v.z;
                    sBuf[(q * 4 + 3) * 256 + tid] = v.w;
                }
            }
            __syncthreads();

            const float* weB = sWeC + og * 8;
#pragma unroll
            for (int k = 0; k < 32; ++k) {
                float4 m = *(const float4*)&sBuf[k * 256 + 4 * eg]; // conflict-free b128
                float4 w0 = *(const float4*)&weB[k * 32];           // broadcast
                float4 w1 = *(const float4*)&weB[k * 32 + 4];
                float ma[4] = { m.x, m.y, m.z, m.w };
                float wv[8] = { w0.x, w0.y, w0.z, w0.w, w1.x, w1.y, w1.z, w1.w };
#pragma unroll
                for (int i = 0; i < 4; ++i)
#pragma unroll
                    for (int j = 0; j < 8; ++j) acc[i][j] += ma[i] * wv[j];
            }
        }

        // bias + relu + block-local accumulate (LDS atomics)
#pragma unroll
        for (int i = 0; i < 4; ++i) {
            int ln = sLn[4 * eg + i];
            if (ln >= 0) {
                float* row = &sMsgAcc[ln * 33 + og * 8];
#pragma unroll
                for (int j = 0; j < 8; ++j) {
                    float v = acc[i][j] + ebias[j];
                    v = v > 0.f ? v : 0.f;
                    atomicAdd(&row[j], v);
                }
            }
        }
    }

    // ================= Phase 2: node GEMM =================
    float* sInT = sBuf;          // [32][64]
    float* sWn  = sBuf + 2048;   // [32][128]

    const int ng  = tid & 31;    // nodes 2*ng, 2*ng+1
    const int og2 = tid >> 5;    // cols og2*16 .. +15

    float acc2[2][16];
#pragma unroll
    for (int i = 0; i < 2; ++i)
#pragma unroll
        for (int j = 0; j < 16; ++j) acc2[i][j] = 0.f;

    // 5 K-chunks of 32: [0,128)=nf, [128,160)=msg (from LDS)
    for (int kc = 0; kc < 5; ++kc) {
        __syncthreads();   // kc=0: edge-phase sBuf reads + sMsgAcc atomics done
        {
            const float4* w4 = (const float4*)(Wn + (size_t)kc * 32 * 128);
            float4* s4 = (float4*)sWn;
#pragma unroll
            for (int i = 0; i < 4; ++i) s4[tid + 256 * i] = w4[tid + 256 * i];
        }
        {
            int nl = tid >> 2;          // 0..63
            int q  = tid & 3;
            if (kc < 4) {
                int n = n0b + nl; if (n >= N_NODES) n = N_NODES - 1;
                const float4* src4 = (const float4*)(nf + (size_t)n * F_NODE + kc * 32);
#pragma unroll
                for (int h = 0; h < 2; ++h) {
                    float4 v = src4[q * 2 + h];
                    int kl = q * 8 + h * 4;
                    sInT[(kl + 0) * 64 + nl] = v.x;
                    sInT[(kl + 1) * 64 + nl] = v.y;
                    sInT[(kl + 2) * 64 + nl] = v.z;
                    sInT[(kl + 3) * 64 + nl] = v.w;
                }
            } else {
                // transpose LDS msg accumulator [node][33] -> sInT [k][node]
#pragma unroll
                for (int h = 0; h < 8; ++h) {
                    int kl = q * 8 + h;
                    sInT[kl * 64 + nl] = sMsgAcc[nl * 33 + kl];
                }
            }
        }
        __syncthreads();

#pragma unroll
        for (int k = 0; k < 32; ++k) {
            float2 m = *(const float2*)&sInT[k * 64 + 2 * ng];
            const float* wr = &sWn[k * 128 + og2 * 16];
            float4 w0 = *(const float4*)&wr[0];
            float4 w1 = *(const float4*)&wr[4];
            float4 w2 = *(const float4*)&wr[8];
            float4 w3 = *(const float4*)&wr[12];
            float ma[2] = { m.x, m.y };
            float wv[16] = { w0.x,w0.y,w0.z,w0.w, w1.x,w1.y,w1.z,w1.w,
                             w2.x,w2.y,w2.z,w2.w, w3.x,w3.y,w3.z,w3.w };
#pragma unroll
            for (int i = 0; i < 2; ++i)
#pragma unroll
                for (int j = 0; j < 16; ++j) acc2[i][j] += ma[i] * wv[j];
        }
    }

    float nbias[16];
#pragma unroll
    for (int j = 0; j < 16; ++j) nbias[j] = bn[og2 * 16 + j];

#pragma unroll
    for (int i = 0; i < 2; ++i) {
        int n = n0b + 2 * ng + i;
        if (n < N_NODES) {
            float* dst = out + (size_t)n * F_NODE + og2 * 16;
#pragma unroll
            for (int j = 0; j < 16; j += 4) {
                float4 v;
                v.x = fmaxf(acc2[i][j + 0] + nbias[j + 0], 0.f);
                v.y = fmaxf(acc2[i][j + 1] + nbias[j + 1], 0.f);
                v.z = fmaxf(acc2[i][j + 2] + nbias[j + 2], 0.f);
                v.w = fmaxf(acc2[i][j + 3] + nbias[j + 3], 0.f);
                *(float4*)(dst + j) = v;
            }
        }
    }
}

extern "C" void kernel_launch(void* const* d_in, const int* in_sizes, int n_in,
                              void* d_out, int out_size, void* d_ws, size_t ws_size,
                              hipStream_t stream) {
    const float* nf  = (const float*)d_in[0];
    const int*   idx = (const int*)d_in[1];
    const float* ef  = (const float*)d_in[2];
    const float* We  = (const float*)d_in[3];
    const float* be  = (const float*)d_in[4];
    const float* Wn  = (const float*)d_in[5];
    const float* bn  = (const float*)d_in[6];
    float* out = (float*)d_out;

    // workspace: 2.6 MB total — strictly within the 6.4 MB round-1-proven
    // envelope (rounds 2/3 used 9.2 MB and killed the container: suspected
    // ws overflow -> GPU memory fault).
    int* deg_cursor = (int*)d_ws;                // 50000 ints (deg -> cursor)
    int* perm       = deg_cursor + N_NODES;      // 600000 ints

    hipMemsetAsync(deg_cursor, 0, (size_t)N_NODES * sizeof(int), stream);

    count_kernel<<<(N_EDGES + 255) / 256, 256, 0, stream>>>(idx, deg_cursor);
    scan_kernel<<<1, 1024, 0, stream>>>(deg_cursor);
    scatter_kernel<<<(N_EDGES + 255) / 256, 256, 0, stream>>>(idx, deg_cursor, perm);

    fused_kernel<<<(N_NODES + NPB - 1) / NPB, 256, 0, stream>>>(
        nf, idx, ef, We, be, Wn, bn, perm, deg_cursor, out);
}